// Round 9
// baseline (932.645 us; speedup 1.0000x reference)
//
#include <hip/hip_runtime.h>
#include <hip/hip_bf16.h>
#include <stdint.h>

#define BATCH_N 65536
#define KDIM 1024
#define NTOT 1536

typedef __bf16 bf16x8 __attribute__((ext_vector_type(8)));
typedef float f32x4 __attribute__((ext_vector_type(4)));
typedef unsigned short u16x8 __attribute__((ext_vector_type(8)));

__device__ __forceinline__ unsigned short f2bf(float f) {
    unsigned u = __builtin_bit_cast(unsigned, f);
    u += 0x7FFFu + ((u >> 16) & 1u);   // round-to-nearest-even
    return (unsigned short)(u >> 16);
}

// ---------------------------------------------------------------------------
// Kernel 1: Wt[n][k] = W_{n/512}[k][n%512] bf16, pre-swizzled k ^= (n&7)<<3
// (elem) so linear global_load_lds staging yields the swizzled LDS layout.
// ---------------------------------------------------------------------------
__global__ __launch_bounds__(256) void wconv_kernel(
    const float* __restrict__ Wq, const float* __restrict__ Ws,
    const float* __restrict__ Wk, unsigned short* __restrict__ wt)
{
    const int gt = blockIdx.x * 256 + threadIdx.x;   // 0..393215
    const int n  = gt % NTOT;
    const int kb = (gt / NTOT) * 4;
    const float* W = (n < 512) ? Wq : ((n < 1024) ? Ws : Wk);
    const int nn = n & 511;
    ushort4 o;
    o.x = f2bf(W[(size_t)(kb + 0) * 512 + nn]);
    o.y = f2bf(W[(size_t)(kb + 1) * 512 + nn]);
    o.z = f2bf(W[(size_t)(kb + 2) * 512 + nn]);
    o.w = f2bf(W[(size_t)(kb + 3) * 512 + nn]);
    const int ksw = kb ^ ((n & 7) << 3);
    *(ushort4*)(wt + (size_t)n * KDIM + ksw) = o;
}

// ---------------------------------------------------------------------------
// Kernel 2: csum[n] = colsum of W (fp32, deterministic, no atomics).
// n in 0..1535 (global col index: 0-511 Wq, 512-1023 Ws, 1024-1535 Wk).
// ---------------------------------------------------------------------------
__global__ __launch_bounds__(256) void colsum_kernel(
    const float* __restrict__ Wq, const float* __restrict__ Ws,
    const float* __restrict__ Wk, float* __restrict__ csum)
{
    const int gt = blockIdx.x * 256 + threadIdx.x;   // 0..1535
    const float* W = (gt < 512) ? Wq : ((gt < 1024) ? Ws : Wk);
    const int n = gt & 511;
    float s0 = 0.f, s1 = 0.f, s2 = 0.f, s3 = 0.f;
    #pragma unroll 4
    for (int k = 0; k < 1024; k += 4) {
        s0 += W[(size_t)(k + 0) * 512 + n];
        s1 += W[(size_t)(k + 1) * 512 + n];
        s2 += W[(size_t)(k + 2) * 512 + n];
        s3 += W[(size_t)(k + 3) * 512 + n];
    }
    csum[gt] = (s0 + s1) + (s2 + s3);
}

// ---------------------------------------------------------------------------
// Kernel 3: FUSED gather + GEMM + rank-1 + bias + sigmoid.
//   out[b][n] = sigmoid( emb[id_b]@W + rowsum(mem[id_b])*csum[n] + bias[n] )
//   128x128x64 tile, 256 thr = 4 waves (2x2), per-wave 64x64.
//   A-path: per K-step gather emb f32 slice (8 float4/thread, 2 thr/row),
//     convert bf16, swizzled ds_write into the A double-buffer (T14 style:
//     loads issued at step top, consumed next step top -> 1 full step lead).
//   B-path: global_load_lds from pre-swizzled Wt (r2-proven).
//   rowsum side-channel: 8 float4/thread/step from mem[id], reduced in the
//     MFMA shadow; only needed at the epilogue (infinite slack).
//   Sync: ONE {vmcnt(0) lgkmcnt(0); s_barrier} per K-step. No counted vmcnt,
//   no cross-wave ledger: every hazard is closed by the full drain+barrier.
// ---------------------------------------------------------------------------
#define BM 128
#define BN 128
#define BK 64
#define MT (BATCH_N / BM)   // 512
#define NT (NTOT / BN)      // 12
#define NWG (MT * NT)       // 6144 = 8 * 768, 768 % 12 == 0 -> bijective

#define SYNC() do { asm volatile("s_waitcnt vmcnt(0) lgkmcnt(0)" ::: "memory"); \
                    asm volatile("s_barrier" ::: "memory"); } while (0)
#define AS1 __attribute__((address_space(1)))
#define AS3 __attribute__((address_space(3)))

__global__ __launch_bounds__(256, 2) void gemm_kernel(
    const int*   __restrict__ ids,
    const float* __restrict__ mem,
    const float* __restrict__ emb,
    const unsigned short* __restrict__ Wt,   // [1536][1024] bf16, swizzled
    const float* __restrict__ csum,          // [1536] colsum(W) f32
    const float* __restrict__ bq, const float* __restrict__ bs,
    const float* __restrict__ bk, float* __restrict__ out)
{
    __shared__ __align__(16) unsigned short sA[2 * 8192];   // 2 x 16 KiB
    __shared__ __align__(16) unsigned short sB[2 * 8192];   // 2 x 16 KiB
    __shared__ float rsLDS[128];

    const int tid  = threadIdx.x;
    const int xcd  = blockIdx.x & 7;
    const int idx  = blockIdx.x >> 3;
    const int wgid = xcd * (NWG / 8) + idx;
    const int nt   = wgid % NT;              // n fastest: A-panel L2 reuse
    const int mt   = wgid / NT;
    const int m0   = mt * BM;
    const int n0   = nt * BN;
    const int wid  = tid >> 6;
    const int lane = tid & 63;
    const int wm   = wid >> 1;               // 0..1
    const int wn   = wid & 1;                // 0..1
    const int r16  = lane & 15;
    const int kb0  = (lane >> 4) << 4;       // 0,16,32,48 (bytes)
    const int ksw  = (r16 & 7) << 4;         // LDS XOR swizzle (bytes)

    // A-staging role: 2 threads per row; arow 0..127, ah = k-half
    const int arow = tid >> 1;
    const int ah   = tid & 1;
    const int gid  = ids[m0 + arow];
    const float4* gE = (const float4*)(emb + (size_t)gid * KDIM + ah * 32);
    const float4* gM = (const float4*)(mem + (size_t)gid * KDIM + ah * 32);

    // B-staging source (r2 pattern)
    const unsigned short* gB = Wt + (size_t)(n0 + (tid >> 3)) * KDIM + (tid & 7) * 8;
    const int ldstB = (tid & 192) * 8;       // wave-uniform elem offset

    f32x4 acc[4][4];
    #pragma unroll
    for (int i = 0; i < 4; i++)
        #pragma unroll
        for (int j = 0; j < 4; j++)
            acc[i][j] = f32x4{0.f, 0.f, 0.f, 0.f};

    bf16x8 af[4][2], bfr[4][2];
    float4 ev[8], mv[8];
    float rsum = 0.f;

#define LOAD_E(tt) do {                                                         \
    _Pragma("unroll")                                                            \
    for (int c = 0; c < 8; ++c) ev[c] = gE[(size_t)(tt) * 16 + c];               \
} while (0)
#define LOAD_M(tt) do {                                                         \
    _Pragma("unroll")                                                            \
    for (int c = 0; c < 8; ++c) mv[c] = gM[(size_t)(tt) * 16 + c];               \
} while (0)
#define REDUCE_M() do {                                                         \
    float a0 = 0.f, a1 = 0.f;                                                    \
    _Pragma("unroll")                                                            \
    for (int c = 0; c < 4; ++c) {                                                \
        a0 += mv[2*c].x + mv[2*c].y + mv[2*c].z + mv[2*c].w;                     \
        a1 += mv[2*c+1].x + mv[2*c+1].y + mv[2*c+1].z + mv[2*c+1].w;             \
    }                                                                            \
    rsum += a0 + a1;                                                             \
} while (0)
// convert ev (slice in regs) -> swizzled bf16 ds_write into A slot
#define WRITE_A(slot) do {                                                      \
    char* base = (char*)sA + (slot) * 16384 + arow * 128;                        \
    _Pragma("unroll")                                                            \
    for (int c = 0; c < 4; ++c) {                                                \
        u16x8 w;                                                                 \
        float4 p = ev[2*c], q = ev[2*c+1];                                       \
        w[0]=f2bf(p.x); w[1]=f2bf(p.y); w[2]=f2bf(p.z); w[3]=f2bf(p.w);          \
        w[4]=f2bf(q.x); w[5]=f2bf(q.y); w[6]=f2bf(q.z); w[7]=f2bf(q.w);          \
        *(u16x8*)(base + ((ah * 64 + c * 16) ^ ((arow & 7) << 4))) = w;          \
    }                                                                            \
} while (0)
#define DMA_B(slot, tt) do {                                                    \
    _Pragma("unroll")                                                            \
    for (int c = 0; c < 4; ++c)                                                  \
        __builtin_amdgcn_global_load_lds(                                        \
            (const AS1 void*)(gB + (size_t)c * 32 * KDIM + (tt) * BK),           \
            (AS3 void*)(&sB[(slot) * 8192 + c * 2048 + ldstB]), 16, 0, 0);       \
} while (0)
#define RD_FRAGS(slot) do {                                                     \
    const char* pa = (const char*)sA + (slot) * 16384;                           \
    const char* pb = (const char*)sB + (slot) * 16384;                           \
    _Pragma("unroll")                                                            \
    for (int i = 0; i < 4; ++i)                                                  \
        _Pragma("unroll")                                                        \
        for (int kk = 0; kk < 2; ++kk)                                           \
            af[i][kk] = *(const bf16x8*)(pa + (wm * 64 + i * 16 + r16) * 128     \
                                           + ((kk * 64 + kb0) ^ ksw));           \
    _Pragma("unroll")                                                            \
    for (int j = 0; j < 4; ++j)                                                  \
        _Pragma("unroll")                                                        \
        for (int kk = 0; kk < 2; ++kk)                                           \
            bfr[j][kk] = *(const bf16x8*)(pb + (wn * 64 + j * 16 + r16) * 128    \
                                            + ((kk * 64 + kb0) ^ ksw));          \
} while (0)
#define MM() do {                                                               \
    _Pragma("unroll")                                                            \
    for (int i = 0; i < 4; ++i)                                                  \
        _Pragma("unroll")                                                        \
        for (int j = 0; j < 4; ++j)                                              \
            _Pragma("unroll")                                                    \
            for (int kk = 0; kk < 2; ++kk)                                       \
                acc[i][j] = __builtin_amdgcn_mfma_f32_16x16x32_bf16(             \
                    af[i][kk], bfr[j][kk], acc[i][j], 0, 0, 0);                  \
} while (0)

    // ---- prologue: build slot0 (tile 0); leave ev = slice 1 ----
    LOAD_E(0);
    DMA_B(0, 0);
    WRITE_A(0);                  // compiler waits ev loads, then writes LDS
    LOAD_E(1);
    SYNC();                      // slot0 ready (A written + drained, B landed)

    // ---- main loop: 16 K-steps.  Invariants at entry of step t:
    //   slot (t&1) holds tile t;  ev holds slice t+1 (t<=14);
    //   mv holds chunk t-1 (t>=1). ----
    #pragma unroll
    for (int t = 0; t < 16; ++t) {
        const int s = t & 1, s1 = s ^ 1;
        if (t < 15) WRITE_A(s1);             // slice t+1 -> other slot
        if (t < 15) DMA_B(s1, t + 1);
        if (t >= 1) REDUCE_M();              // chunk t-1
        LOAD_M(t);                           // chunk t (consumed next step)
        if (t + 2 < 16) LOAD_E(t + 2);       // slice t+2 (consumed next step)
        RD_FRAGS(s);
        MM();                                // compiler inserts lgkm waits
        SYNC();
    }
    REDUCE_M();                              // chunk 15

    // ---- rowsum finalize: pair lanes (2r,2r+1) hold half-sums ----
    const float rfull = rsum + __shfl_xor(rsum, 1, 64);
    if (ah == 0) rsLDS[arow] = rfull;
    __syncthreads();

    // ---- epilogue: acc + rowsum*csum + bias, sigmoid, NT stores ----
    // C/D layout: col=lane&15, row=(lane>>4)*4+reg  [m89/m91]
    const int grp = n0 >> 9;                        // 0=q, 1=s, 2=k
    const float* bias = (grp == 0) ? bq : ((grp == 1) ? bs : bk);
    float* obase = out + (size_t)grp * ((size_t)BATCH_N * 512);
    const int nb = n0 & 511;
    #pragma unroll
    for (int j = 0; j < 4; ++j) {
        const int coll = nb + wn * 64 + j * 16 + r16;        // local col
        const float bv = bias[coll];
        const float cv = csum[n0 + wn * 64 + j * 16 + r16];  // global col
        #pragma unroll
        for (int i = 0; i < 4; ++i) {
            const int rloc = wm * 64 + i * 16 + ((lane >> 4) << 2);
            #pragma unroll
            for (int r = 0; r < 4; ++r) {
                const float rs = rsLDS[rloc + r];
                float v = acc[i][j][r] + rs * cv + bv;
                v = 1.0f / (1.0f + __expf(-v));
                __builtin_nontemporal_store(v, &obase[(size_t)(m0 + rloc + r) * 512 + coll]);
            }
        }
    }
#undef LOAD_E
#undef LOAD_M
#undef REDUCE_M
#undef WRITE_A
#undef DMA_B
#undef RD_FRAGS
#undef MM
}

extern "C" void kernel_launch(void* const* d_in, const int* in_sizes, int n_in,
                              void* d_out, int out_size, void* d_ws, size_t ws_size,
                              hipStream_t stream) {
    const int*   ids = (const int*)d_in[0];
    const float* mem = (const float*)d_in[1];
    const float* emb = (const float*)d_in[2];
    const float* Wq  = (const float*)d_in[3];
    const float* bq  = (const float*)d_in[4];
    const float* Ws  = (const float*)d_in[5];
    const float* bs  = (const float*)d_in[6];
    const float* Wk  = (const float*)d_in[7];
    const float* bk  = (const float*)d_in[8];
    float* out = (float*)d_out;

    unsigned short* wt = (unsigned short*)d_ws;              // 1536*1024 bf16 = 3 MiB
    float* csum = (float*)(wt + (size_t)NTOT * KDIM);        // 1536 f32

    hipLaunchKernelGGL(wconv_kernel, dim3(NTOT), dim3(256), 0, stream, Wq, Ws, Wk, wt);
    hipLaunchKernelGGL(colsum_kernel, dim3(6), dim3(256), 0, stream, Wq, Ws, Wk, csum);
    hipLaunchKernelGGL(gemm_kernel, dim3(NWG), dim3(256), 0, stream,
                       ids, mem, emb, wt, csum, bq, bs, bk, out);
}

// Round 10
// 393.164 us; speedup vs baseline: 2.3722x; 2.3722x over previous
//
#include <hip/hip_runtime.h>
#include <hip/hip_bf16.h>
#include <stdint.h>

#define BATCH_N 65536
#define KDIM 1024
#define NTOT 1536

typedef __bf16 bf16x8 __attribute__((ext_vector_type(8)));
typedef float f32x4 __attribute__((ext_vector_type(4)));

__device__ __forceinline__ unsigned short f2bf(float f) {
    unsigned u = __builtin_bit_cast(unsigned, f);
    u += 0x7FFFu + ((u >> 16) & 1u);   // round-to-nearest-even
    return (unsigned short)(u >> 16);
}

// ---------------------------------------------------------------------------
// Kernel 1: x[b][k] = sum(node_memories[id]) + node_embedding[id][k], bf16,
// pre-swizzled (k ^= (b&7)<<3).  One WAVE per row; each lane owns 4 float4
// chunks at k = q*256 + lane*4 (full 1024 coverage), butterfly reduce.
// ---------------------------------------------------------------------------
__global__ __launch_bounds__(256) void prep_kernel(
    const int* __restrict__ ids,
    const float* __restrict__ mem,
    const float* __restrict__ emb,
    unsigned short* __restrict__ x)
{
    const int b    = blockIdx.x * 4 + (threadIdx.x >> 6);
    const int lane = threadIdx.x & 63;
    const int id   = ids[b];
    const float4* m4 = (const float4*)(mem + (size_t)id * KDIM) + lane;
    const float4* e4 = (const float4*)(emb + (size_t)id * KDIM) + lane;
    float4 v0 = m4[0];
    float4 v1 = m4[64];
    float4 v2 = m4[128];
    float4 v3 = m4[192];
    float s = (v0.x + v0.y + v0.z + v0.w) + (v1.x + v1.y + v1.z + v1.w)
            + (v2.x + v2.y + v2.z + v2.w) + (v3.x + v3.y + v3.z + v3.w);
    #pragma unroll
    for (int off = 1; off < 64; off <<= 1) s += __shfl_xor(s, off, 64);
    unsigned short* xb = x + (size_t)b * KDIM;
    #pragma unroll
    for (int q = 0; q < 4; ++q) {
        float4 e = e4[q * 64];
        ushort4 o;
        o.x = f2bf(s + e.x);
        o.y = f2bf(s + e.y);
        o.z = f2bf(s + e.z);
        o.w = f2bf(s + e.w);
        const int k   = q * 256 + lane * 4;
        const int ksw = k ^ ((b & 7) << 3);
        *(ushort4*)(xb + ksw) = o;
    }
}

// ---------------------------------------------------------------------------
// Kernel 2: Wt[n][k] = W_{n/512}[k][n%512] in bf16, same pre-swizzle on k.
// ---------------------------------------------------------------------------
__global__ __launch_bounds__(256) void wconv_kernel(
    const float* __restrict__ Wq, const float* __restrict__ Ws,
    const float* __restrict__ Wk, unsigned short* __restrict__ wt)
{
    const int gt = blockIdx.x * 256 + threadIdx.x;   // 0..393215
    const int n  = gt % NTOT;
    const int kb = (gt / NTOT) * 4;
    const float* W = (n < 512) ? Wq : ((n < 1024) ? Ws : Wk);
    const int nn = n & 511;
    ushort4 o;
    o.x = f2bf(W[(size_t)(kb + 0) * 512 + nn]);
    o.y = f2bf(W[(size_t)(kb + 1) * 512 + nn]);
    o.z = f2bf(W[(size_t)(kb + 2) * 512 + nn]);
    o.w = f2bf(W[(size_t)(kb + 3) * 512 + nn]);
    const int ksw = kb ^ ((n & 7) << 3);
    *(ushort4*)(wt + (size_t)n * KDIM + ksw) = o;
}

// ---------------------------------------------------------------------------
// Kernel 3: m201-faithful 256x256 8-phase GEMM + bias + sigmoid.
//   512 thr = 8 waves (2M x 4N); per-wave 128x64 output as 2x2 quadrants
//   (qa,qb = A/B tile halves): A rows qa*128+wm*64+i*16, B cols
//   qb*128+wn*32+j*16.  Phase order per K-tile: (0,0),(0,1),(1,1),(1,0).
//   Both B quadrant sets held in regs (bfr0/bfr1); A set reloaded at qa flip.
//   LDS 128 KiB: {A,B} x [2 slots][2 halves][128][64] bf16, XOR-swizzled via
//   pre-swizzled global (T2).  One half-tile staged per phase (2 DMA instrs),
//   exactly one phase after its last reader: P1:Bh0(s1,2t+1) P2:Ah0(s0,2t+2)
//   P3:Bh1(s0,2t+2) P4:Ah1(s0,2t+2) P5:Bh0(s0,2t+2) P6:Ah0(s1,2t+3)
//   P7:Bh1(s1,2t+3) P8:Ah1(s1,2t+3).  vmcnt(6) ONLY at P4/P8 (3 half-tiles
//   in flight).  Ledger verified: at P4's vm6 in-flight={P2,P3,P4} so tile
//   2t+1 fully retired before P5 reads it; at P8's vm6 in-flight={P6,P7,P8}
//   so tile 2t+2 fully retired before next-P1.  WAR: every overwrite is 1+
//   phase (2 barriers) after its last ds_read's lgkmcnt(0).
//   Prologue: 7 half-tiles + vmcnt(0).  Tail iter: vmcnt(0) at P4.
// ---------------------------------------------------------------------------
#define BM 256
#define BN 256
#define BK 64
#define MT (BATCH_N / BM)   // 256
#define NT (NTOT / BN)      // 6
#define NWG (MT * NT)       // 1536 = 8 * 192, 192 % 6 == 0 -> bijective

#define BAR() asm volatile("s_barrier" ::: "memory")
#define LGKM0() asm volatile("s_waitcnt lgkmcnt(0)" ::: "memory")
#define VM6() asm volatile("s_waitcnt vmcnt(6)" ::: "memory")
#define VM0() asm volatile("s_waitcnt vmcnt(0)" ::: "memory")
#define AS1 __attribute__((address_space(1)))
#define AS3 __attribute__((address_space(3)))

__global__ __launch_bounds__(512, 2) void gemm_kernel(
    const unsigned short* __restrict__ X,    // [65536][1024] bf16, swizzled
    const unsigned short* __restrict__ Wt,   // [1536][1024]  bf16, swizzled
    const float* __restrict__ bq, const float* __restrict__ bs,
    const float* __restrict__ bk, float* __restrict__ out)
{
    __shared__ __align__(16) unsigned short sA[32768];   // 64 KiB
    __shared__ __align__(16) unsigned short sB[32768];   // 64 KiB

    const int tid  = threadIdx.x;
    const int xcd  = blockIdx.x & 7;
    const int idx  = blockIdx.x >> 3;
    const int wgid = xcd * (NWG / 8) + idx;
    const int nt   = wgid % NT;              // n fastest: A-panel L2 reuse
    const int mt   = wgid / NT;
    const int m0   = mt * BM;
    const int n0   = nt * BN;
    const int wid  = tid >> 6;
    const int lane = tid & 63;
    const int wm   = wid >> 2;               // 0..1
    const int wn   = wid & 3;                // 0..3
    const int r16  = lane & 15;
    const int kb0  = (lane >> 4) << 4;       // 0,16,32,48 (bytes)
    const int ksw  = (r16 & 7) << 4;         // LDS XOR swizzle (bytes)

    f32x4 acc[8][4];
    #pragma unroll
    for (int i = 0; i < 8; i++)
        #pragma unroll
        for (int j = 0; j < 4; j++)
            acc[i][j] = f32x4{0.f, 0.f, 0.f, 0.f};

    bf16x8 af[4][2], bfr0[2][2], bfr1[2][2];

    const unsigned short* gA = X  + (size_t)(m0 + (tid >> 3)) * KDIM + (tid & 7) * 8;
    const unsigned short* gB = Wt + (size_t)(n0 + (tid >> 3)) * KDIM + (tid & 7) * 8;
    const int ldst = (tid & 448) * 8;        // wave-uniform LDS elem offset

// stage ONE half-tile (2 DMA instrs/thread)
#define STG_A(slot, h, kt) do {                                                 \
    _Pragma("unroll")                                                            \
    for (int c = 0; c < 2; ++c)                                                  \
        __builtin_amdgcn_global_load_lds(                                        \
            (const AS1 void*)(gA + (size_t)((h) * 128 + c * 64) * KDIM + (kt) * BK), \
            (AS3 void*)(&sA[((slot) * 2 + (h)) * 8192 + c * 4096 + ldst]),       \
            16, 0, 0);                                                           \
} while (0)
#define STG_B(slot, h, kt) do {                                                 \
    _Pragma("unroll")                                                            \
    for (int c = 0; c < 2; ++c)                                                  \
        __builtin_amdgcn_global_load_lds(                                        \
            (const AS1 void*)(gB + (size_t)((h) * 128 + c * 64) * KDIM + (kt) * BK), \
            (AS3 void*)(&sB[((slot) * 2 + (h)) * 8192 + c * 4096 + ldst]),       \
            16, 0, 0);                                                           \
} while (0)

#define LDA(slot, qa) do {                                                      \
    const char* p = (const char*)&sA[((slot) * 2 + (qa)) * 8192];                \
    _Pragma("unroll")                                                            \
    for (int i = 0; i < 4; ++i)                                                  \
        _Pragma("unroll")                                                        \
        for (int kk = 0; kk < 2; ++kk)                                           \
            af[i][kk] = *(const bf16x8*)(p + (wm * 64 + i * 16 + r16) * 128      \
                                           + ((kk * 64 + kb0) ^ ksw));           \
} while (0)
#define LDB(slot, qb, SET) do {                                                 \
    const char* p = (const char*)&sB[((slot) * 2 + (qb)) * 8192];                \
    _Pragma("unroll")                                                            \
    for (int j = 0; j < 2; ++j)                                                  \
        _Pragma("unroll")                                                        \
        for (int kk = 0; kk < 2; ++kk)                                           \
            SET[j][kk] = *(const bf16x8*)(p + (wn * 32 + j * 16 + r16) * 128     \
                                            + ((kk * 64 + kb0) ^ ksw));          \
} while (0)

#define MM(QA, QB, SET) do {                                                    \
    __builtin_amdgcn_s_setprio(1);                                               \
    _Pragma("unroll")                                                            \
    for (int i = 0; i < 4; ++i)                                                  \
        _Pragma("unroll")                                                        \
        for (int j = 0; j < 2; ++j)                                              \
            _Pragma("unroll")                                                    \
            for (int kk = 0; kk < 2; ++kk)                                       \
                acc[(QA) * 4 + i][(QB) * 2 + j] =                                \
                    __builtin_amdgcn_mfma_f32_16x16x32_bf16(                     \
                        af[i][kk], SET[j][kk], acc[(QA) * 4 + i][(QB) * 2 + j],  \
                        0, 0, 0);                                                \
    __builtin_amdgcn_s_setprio(0);                                               \
} while (0)

    // ---- prologue: tile0 full (s0) + tile1 {Ah0,Bh1,Ah1} (s1); skip Bh0(1) ----
    STG_A(0, 0, 0); STG_A(0, 1, 0); STG_B(0, 0, 0); STG_B(0, 1, 0);
    STG_A(1, 0, 1); STG_B(1, 1, 1); STG_A(1, 1, 1);
    VM0();
    BAR();

    // ---- main loop: 7 iterations, tiles (2t, 2t+1) ----
    #pragma unroll 1
    for (int t = 0; t < 7; ++t) {
        const int ka = 2 * t + 1, kb2 = 2 * t + 2, kc = 2 * t + 3;
        // P1
        LDA(0, 0); LDB(0, 0, bfr0); STG_B(1, 0, ka);
        BAR(); LGKM0(); MM(0, 0, bfr0); BAR();
        // P2
        LDB(0, 1, bfr1); STG_A(0, 0, kb2);
        BAR(); LGKM0(); MM(0, 1, bfr1); BAR();
        // P3
        LDA(0, 1); STG_B(0, 1, kb2);
        BAR(); LGKM0(); MM(1, 1, bfr1); BAR();
        // P4
        STG_A(0, 1, kb2);
        BAR(); LGKM0(); MM(1, 0, bfr0); VM6(); BAR();
        // P5
        LDA(1, 0); LDB(1, 0, bfr0); STG_B(0, 0, kb2);
        BAR(); LGKM0(); MM(0, 0, bfr0); BAR();
        // P6
        LDB(1, 1, bfr1); STG_A(1, 0, kc);
        BAR(); LGKM0(); MM(0, 1, bfr1); BAR();
        // P7
        LDA(1, 1); STG_B(1, 1, kc);
        BAR(); LGKM0(); MM(1, 1, bfr1); BAR();
        // P8
        STG_A(1, 1, kc);
        BAR(); LGKM0(); MM(1, 0, bfr0); VM6(); BAR();
    }
    // ---- tail iteration: tiles 14 (s0), 15 (s1) ----
    // P1
    LDA(0, 0); LDB(0, 0, bfr0); STG_B(1, 0, 15);
    BAR(); LGKM0(); MM(0, 0, bfr0); BAR();
    // P2
    LDB(0, 1, bfr1);
    BAR(); LGKM0(); MM(0, 1, bfr1); BAR();
    // P3
    LDA(0, 1);
    BAR(); LGKM0(); MM(1, 1, bfr1); BAR();
    // P4
    BAR(); LGKM0(); MM(1, 0, bfr0); VM0(); BAR();
    // P5
    LDA(1, 0); LDB(1, 0, bfr0);
    BAR(); LGKM0(); MM(0, 0, bfr0); BAR();
    // P6
    LDB(1, 1, bfr1);
    BAR(); LGKM0(); MM(0, 1, bfr1); BAR();
    // P7
    LDA(1, 1);
    BAR(); LGKM0(); MM(1, 1, bfr1); BAR();
    // P8
    BAR(); LGKM0(); MM(1, 0, bfr0);

    // ---- epilogue: bias + sigmoid, nontemporal fp32 stores ----
    // C/D layout: col=lane&15, row=(lane>>4)*4+reg  [m89/m91]
    const int grp = nt >> 1;                        // 0=q, 1=s, 2=k
    const float* bias = (grp == 0) ? bq : ((grp == 1) ? bs : bk);
    float* obase = out + (size_t)grp * ((size_t)BATCH_N * 512);
    const int cb = (nt & 1) * 256;
    #pragma unroll
    for (int qb = 0; qb < 2; ++qb)
        #pragma unroll
        for (int j = 0; j < 2; ++j) {
            const int col = cb + qb * 128 + wn * 32 + j * 16 + r16;
            const float bv = bias[col];
            #pragma unroll
            for (int qa = 0; qa < 2; ++qa)
                #pragma unroll
                for (int i = 0; i < 4; ++i) {
                    const int rbase = m0 + qa * 128 + wm * 64 + i * 16 + ((lane >> 4) << 2);
                    #pragma unroll
                    for (int r = 0; r < 4; ++r) {
                        float v = acc[qa * 4 + i][qb * 2 + j][r] + bv;
                        v = 1.0f / (1.0f + __expf(-v));
                        __builtin_nontemporal_store(v, &obase[(size_t)(rbase + r) * 512 + col]);
                    }
                }
        }
#undef STG_A
#undef STG_B
#undef LDA
#undef LDB
#undef MM
}

extern "C" void kernel_launch(void* const* d_in, const int* in_sizes, int n_in,
                              void* d_out, int out_size, void* d_ws, size_t ws_size,
                              hipStream_t stream) {
    const int*   ids = (const int*)d_in[0];
    const float* mem = (const float*)d_in[1];
    const float* emb = (const float*)d_in[2];
    const float* Wq  = (const float*)d_in[3];
    const float* bq  = (const float*)d_in[4];
    const float* Ws  = (const float*)d_in[5];
    const float* bs  = (const float*)d_in[6];
    const float* Wk  = (const float*)d_in[7];
    const float* bk  = (const float*)d_in[8];
    float* out = (float*)d_out;

    unsigned short* x  = (unsigned short*)d_ws;              // 65536*1024 bf16 = 128 MiB
    unsigned short* wt = x + (size_t)BATCH_N * KDIM;         // 1536*1024  bf16 = 3 MiB

    hipLaunchKernelGGL(wconv_kernel, dim3(NTOT), dim3(256), 0, stream, Wq, Ws, Wk, wt);
    hipLaunchKernelGGL(prep_kernel, dim3(BATCH_N / 4), dim3(256), 0, stream, ids, mem, emb, x);
    hipLaunchKernelGGL(gemm_kernel, dim3(NWG), dim3(512), 0, stream,
                       x, wt, bq, bs, bk, out);
}

// Round 12
// 391.275 us; speedup vs baseline: 2.3836x; 1.0048x over previous
//
#include <hip/hip_runtime.h>
#include <hip/hip_bf16.h>
#include <stdint.h>

#define BATCH_N 65536
#define KDIM 1024
#define NTOT 1536

typedef __bf16 bf16x8 __attribute__((ext_vector_type(8)));
typedef float f32x4 __attribute__((ext_vector_type(4)));

__device__ __forceinline__ unsigned short f2bf(float f) {
    unsigned u = __builtin_bit_cast(unsigned, f);
    u += 0x7FFFu + ((u >> 16) & 1u);   // round-to-nearest-even
    return (unsigned short)(u >> 16);
}

// ---------------------------------------------------------------------------
// Kernel 1: x[b][k] = sum(node_memories[id]) + node_embedding[id][k], bf16,
// pre-swizzled (k ^= (b&7)<<3).  One WAVE per row; each lane owns 4 float4
// chunks at k = q*256 + lane*4, butterfly reduce.
// ---------------------------------------------------------------------------
__global__ __launch_bounds__(256) void prep_kernel(
    const int* __restrict__ ids,
    const float* __restrict__ mem,
    const float* __restrict__ emb,
    unsigned short* __restrict__ x)
{
    const int b    = blockIdx.x * 4 + (threadIdx.x >> 6);
    const int lane = threadIdx.x & 63;
    const int id   = ids[b];
    const float4* m4 = (const float4*)(mem + (size_t)id * KDIM) + lane;
    const float4* e4 = (const float4*)(emb + (size_t)id * KDIM) + lane;
    float4 v0 = m4[0];
    float4 v1 = m4[64];
    float4 v2 = m4[128];
    float4 v3 = m4[192];
    float s = (v0.x + v0.y + v0.z + v0.w) + (v1.x + v1.y + v1.z + v1.w)
            + (v2.x + v2.y + v2.z + v2.w) + (v3.x + v3.y + v3.z + v3.w);
    #pragma unroll
    for (int off = 1; off < 64; off <<= 1) s += __shfl_xor(s, off, 64);
    unsigned short* xb = x + (size_t)b * KDIM;
    #pragma unroll
    for (int q = 0; q < 4; ++q) {
        float4 e = e4[q * 64];
        ushort4 o;
        o.x = f2bf(s + e.x);
        o.y = f2bf(s + e.y);
        o.z = f2bf(s + e.z);
        o.w = f2bf(s + e.w);
        const int k   = q * 256 + lane * 4;
        const int ksw = k ^ ((b & 7) << 3);
        *(ushort4*)(xb + ksw) = o;
    }
}

// ---------------------------------------------------------------------------
// Kernel 2: Wt[n][k] = W_{n/512}[k][n%512] in bf16, same pre-swizzle on k.
// ---------------------------------------------------------------------------
__global__ __launch_bounds__(256) void wconv_kernel(
    const float* __restrict__ Wq, const float* __restrict__ Ws,
    const float* __restrict__ Wk, unsigned short* __restrict__ wt)
{
    const int gt = blockIdx.x * 256 + threadIdx.x;   // 0..393215
    const int n  = gt % NTOT;
    const int kb = (gt / NTOT) * 4;
    const float* W = (n < 512) ? Wq : ((n < 1024) ? Ws : Wk);
    const int nn = n & 511;
    ushort4 o;
    o.x = f2bf(W[(size_t)(kb + 0) * 512 + nn]);
    o.y = f2bf(W[(size_t)(kb + 1) * 512 + nn]);
    o.z = f2bf(W[(size_t)(kb + 2) * 512 + nn]);
    o.w = f2bf(W[(size_t)(kb + 3) * 512 + nn]);
    const int ksw = kb ^ ((n & 7) << 3);
    *(ushort4*)(wt + (size_t)n * KDIM + ksw) = o;
}

// ---------------------------------------------------------------------------
// Kernel 3: 256x256 8-phase GEMM, read-ahead with RACE-SAFE placement.
//   Phase skeleton: { [cross-boundary reads] ; MM(operands read earlier) ;
//                     [read-ahead reads] ; STG one half-tile ; [VM6] ; BAR }
//   RULE (r5/r11 lesson): any LDS read of DMA-staged data sits AFTER the
//   (VM-wait -> s_barrier) pair that collectively retires that DMA.  The
//   VM6-crossing reads therefore open the NEXT phase (post-barrier):
//     P1: rd(af0,bfr0 of s0) MM1 rd(bfr1 s0)  STG_B(s1h0,2t+1)      BAR
//     P2:                    MM2 rd(af1 s0)   STG_A(s0h0,2t+2)      BAR
//     P3:                    MM3              STG_B(s0h1,2t+2)      BAR
//     P4:                    MM4              STG_A(s0h1',2t+2) VM6 BAR
//     P5: rd(af0,bfr0 of s1) MM5 rd(bfr1 s1)  STG_B(s0h0,2t+2)      BAR
//     P6:                    MM6 rd(af1 s1)   STG_A(s1h0,2t+3)      BAR
//     P7:                    MM7              STG_B(s1h1,2t+3)      BAR
//     P8:                    MM8              STG_A(s1h1',2t+3) VM6 BAR
//   MFMA order (e=2t s0, o=2t+1 s1): M1 e(0,0) M2 e(0,1) M3 e(1,1) M4 e(1,0)
//   then same for o.  No manual lgkmcnt -- reads are plain loads, compiler
//   inserts counted waits; P2/P3/P6/P7 operands are read a full phase early.
//   RAW ledger (2 DMA/half-tile, newest-6 kept by VM6): P4's VM6 retires P1
//   and all older -> tile o fully landed before P5-start reads.  P8's VM6
//   retires P2..P5 -> tile 2t+2 fully landed before next P1-start reads.
//   WAR: every staged overwrite targets LDS whose last ds_read was serviced
//   before the preceding phase's MM issue (register dep) -> before that
//   phase's barrier -> >=1 barrier before the DMA issues.
// ---------------------------------------------------------------------------
#define BM 256
#define BN 256
#define BK 64
#define MT (BATCH_N / BM)   // 256
#define NT (NTOT / BN)      // 6
#define NWG (MT * NT)       // 1536 = 8 * 192, 192 % 6 == 0 -> bijective

#define BAR() asm volatile("s_barrier" ::: "memory")
#define VM6() asm volatile("s_waitcnt vmcnt(6)" ::: "memory")
#define VM0() asm volatile("s_waitcnt vmcnt(0)" ::: "memory")
#define AS1 __attribute__((address_space(1)))
#define AS3 __attribute__((address_space(3)))

__global__ __launch_bounds__(512, 2) void gemm_kernel(
    const unsigned short* __restrict__ X,    // [65536][1024] bf16, swizzled
    const unsigned short* __restrict__ Wt,   // [1536][1024]  bf16, swizzled
    const float* __restrict__ bq, const float* __restrict__ bs,
    const float* __restrict__ bk, float* __restrict__ out)
{
    __shared__ __align__(16) unsigned short sA[32768];   // 64 KiB
    __shared__ __align__(16) unsigned short sB[32768];   // 64 KiB

    const int tid  = threadIdx.x;
    const int xcd  = blockIdx.x & 7;
    const int idx  = blockIdx.x >> 3;
    const int wgid = xcd * (NWG / 8) + idx;
    const int nt   = wgid % NT;              // n fastest: A-panel L2 reuse
    const int mt   = wgid / NT;
    const int m0   = mt * BM;
    const int n0   = nt * BN;
    const int wid  = tid >> 6;
    const int lane = tid & 63;
    const int wm   = wid >> 2;               // 0..1
    const int wn   = wid & 3;                // 0..3
    const int r16  = lane & 15;
    const int kb0  = (lane >> 4) << 4;       // 0,16,32,48 (bytes)
    const int ksw  = (r16 & 7) << 4;         // LDS XOR swizzle (bytes)

    f32x4 acc[8][4];
    #pragma unroll
    for (int i = 0; i < 8; i++)
        #pragma unroll
        for (int j = 0; j < 4; j++)
            acc[i][j] = f32x4{0.f, 0.f, 0.f, 0.f};

    bf16x8 af0[4][2], af1[4][2], bfr0[2][2], bfr1[2][2];

    const unsigned short* gA = X  + (size_t)(m0 + (tid >> 3)) * KDIM + (tid & 7) * 8;
    const unsigned short* gB = Wt + (size_t)(n0 + (tid >> 3)) * KDIM + (tid & 7) * 8;
    const int ldst = (tid & 448) * 8;        // wave-uniform LDS elem offset

// stage ONE half-tile (2 DMA instrs/thread)
#define STG_A(slot, h, kt) do {                                                 \
    _Pragma("unroll")                                                            \
    for (int c = 0; c < 2; ++c)                                                  \
        __builtin_amdgcn_global_load_lds(                                        \
            (const AS1 void*)(gA + (size_t)((h) * 128 + c * 64) * KDIM + (kt) * BK), \
            (AS3 void*)(&sA[((slot) * 2 + (h)) * 8192 + c * 4096 + ldst]),       \
            16, 0, 0);                                                           \
} while (0)
#define STG_B(slot, h, kt) do {                                                 \
    _Pragma("unroll")                                                            \
    for (int c = 0; c < 2; ++c)                                                  \
        __builtin_amdgcn_global_load_lds(                                        \
            (const AS1 void*)(gB + (size_t)((h) * 128 + c * 64) * KDIM + (kt) * BK), \
            (AS3 void*)(&sB[((slot) * 2 + (h)) * 8192 + c * 4096 + ldst]),       \
            16, 0, 0);                                                           \
} while (0)

#define LDA(SET, slot, qa) do {                                                 \
    const char* p = (const char*)&sA[((slot) * 2 + (qa)) * 8192];                \
    _Pragma("unroll")                                                            \
    for (int i = 0; i < 4; ++i)                                                  \
        _Pragma("unroll")                                                        \
        for (int kk = 0; kk < 2; ++kk)                                           \
            SET[i][kk] = *(const bf16x8*)(p + (wm * 64 + i * 16 + r16) * 128     \
                                            + ((kk * 64 + kb0) ^ ksw));          \
} while (0)
#define LDB(SET, slot, qb) do {                                                 \
    const char* p = (const char*)&sB[((slot) * 2 + (qb)) * 8192];                \
    _Pragma("unroll")                                                            \
    for (int j = 0; j < 2; ++j)                                                  \
        _Pragma("unroll")                                                        \
        for (int kk = 0; kk < 2; ++kk)                                           \
            SET[j][kk] = *(const bf16x8*)(p + (wn * 32 + j * 16 + r16) * 128     \
                                            + ((kk * 64 + kb0) ^ ksw));          \
} while (0)

#define MM(QA, QB, ASET, BSET) do {                                             \
    __builtin_amdgcn_s_setprio(1);                                               \
    _Pragma("unroll")                                                            \
    for (int i = 0; i < 4; ++i)                                                  \
        _Pragma("unroll")                                                        \
        for (int j = 0; j < 2; ++j)                                              \
            _Pragma("unroll")                                                    \
            for (int kk = 0; kk < 2; ++kk)                                       \
                acc[(QA) * 4 + i][(QB) * 2 + j] =                                \
                    __builtin_amdgcn_mfma_f32_16x16x32_bf16(                     \
                        ASET[i][kk], BSET[j][kk],                                \
                        acc[(QA) * 4 + i][(QB) * 2 + j], 0, 0, 0);               \
    __builtin_amdgcn_s_setprio(0);                                               \
} while (0)

    // ---- prologue: tile0 full (s0) + tile1 {Ah0,Bh1,Ah1} (s1) ----
    STG_A(0, 0, 0); STG_A(0, 1, 0); STG_B(0, 0, 0); STG_B(0, 1, 0);
    STG_A(1, 0, 1); STG_B(1, 1, 1); STG_A(1, 1, 1);
    VM0();
    BAR();

    // ---- main loop: 7 iterations, tiles (2t in s0, 2t+1 in s1) ----
    #pragma unroll 1
    for (int t = 0; t < 7; ++t) {
        const int ka = 2 * t + 1, kb2 = 2 * t + 2, kc = 2 * t + 3;
        // P1  (reads of s0 are safe: behind prev VM6+BAR / prologue VM0+BAR)
        LDA(af0, 0, 0); LDB(bfr0, 0, 0);
        MM(0, 0, af0, bfr0);
        LDB(bfr1, 0, 1); STG_B(1, 0, ka);                        BAR();
        // P2
        MM(0, 1, af0, bfr1);
        LDA(af1, 0, 1); STG_A(0, 0, kb2);                        BAR();
        // P3
        MM(1, 1, af1, bfr1); STG_B(0, 1, kb2);                   BAR();
        // P4
        MM(1, 0, af1, bfr0); STG_A(0, 1, kb2); VM6();            BAR();
        // P5  (reads of s1: safe behind P4's VM6+BAR)
        LDA(af0, 1, 0); LDB(bfr0, 1, 0);
        MM(0, 0, af0, bfr0);
        LDB(bfr1, 1, 1); STG_B(0, 0, kb2);                       BAR();
        // P6
        MM(0, 1, af0, bfr1);
        LDA(af1, 1, 1); STG_A(1, 0, kc);                         BAR();
        // P7
        MM(1, 1, af1, bfr1); STG_B(1, 1, kc);                    BAR();
        // P8
        MM(1, 0, af1, bfr0); STG_A(1, 1, kc); VM6();             BAR();
    }
    // ---- tail: tiles 14 (s0), 15 (s1) ----
    // T1
    LDA(af0, 0, 0); LDB(bfr0, 0, 0);
    MM(0, 0, af0, bfr0);
    LDB(bfr1, 0, 1); STG_B(1, 0, 15);                            BAR();
    // T2
    MM(0, 1, af0, bfr1); LDA(af1, 0, 1);                         BAR();
    // T3
    MM(1, 1, af1, bfr1);                                         BAR();
    // T4
    MM(1, 0, af1, bfr0); VM0();                                  BAR();
    // T5
    LDA(af0, 1, 0); LDB(bfr0, 1, 0);
    MM(0, 0, af0, bfr0);
    LDB(bfr1, 1, 1);                                             BAR();
    // T6
    MM(0, 1, af0, bfr1); LDA(af1, 1, 1);                         BAR();
    // T7
    MM(1, 1, af1, bfr1);                                         BAR();
    // T8
    MM(1, 0, af1, bfr0);

    // ---- epilogue: bias + sigmoid, nontemporal fp32 stores ----
    // C/D layout: col=lane&15, row=(lane>>4)*4+reg  [m89/m91]
    const int grp = nt >> 1;                        // 0=q, 1=s, 2=k
    const float* bias = (grp == 0) ? bq : ((grp == 1) ? bs : bk);
    float* obase = out + (size_t)grp * ((size_t)BATCH_N * 512);
    const int cb = (nt & 1) * 256;
    #pragma unroll
    for (int qb = 0; qb < 2; ++qb)
        #pragma unroll
        for (int j = 0; j < 2; ++j) {
            const int col = cb + qb * 128 + wn * 32 + j * 16 + r16;
            const float bv = bias[col];
            #pragma unroll
            for (int qa = 0; qa < 2; ++qa)
                #pragma unroll
                for (int i = 0; i < 4; ++i) {
                    const int rbase = m0 + qa * 128 + wm * 64 + i * 16 + ((lane >> 4) << 2);
                    #pragma unroll
                    for (int r = 0; r < 4; ++r) {
                        float v = acc[qa * 4 + i][qb * 2 + j][r] + bv;
                        v = 1.0f / (1.0f + __expf(-v));
                        __builtin_nontemporal_store(v, &obase[(size_t)(rbase + r) * 512 + col]);
                    }
                }
        }
#undef STG_A
#undef STG_B
#undef LDA
#undef LDB
#undef MM
}

extern "C" void kernel_launch(void* const* d_in, const int* in_sizes, int n_in,
                              void* d_out, int out_size, void* d_ws, size_t ws_size,
                              hipStream_t stream) {
    const int*   ids = (const int*)d_in[0];
    const float* mem = (const float*)d_in[1];
    const float* emb = (const float*)d_in[2];
    const float* Wq  = (const float*)d_in[3];
    const float* bq  = (const float*)d_in[4];
    const float* Ws  = (const float*)d_in[5];
    const float* bs  = (const float*)d_in[6];
    const float* Wk  = (const float*)d_in[7];
    const float* bk  = (const float*)d_in[8];
    float* out = (float*)d_out;

    unsigned short* x  = (unsigned short*)d_ws;              // 65536*1024 bf16 = 128 MiB
    unsigned short* wt = x + (size_t)BATCH_N * KDIM;         // 1536*1024  bf16 = 3 MiB

    hipLaunchKernelGGL(wconv_kernel, dim3(NTOT), dim3(256), 0, stream, Wq, Ws, Wk, wt);
    hipLaunchKernelGGL(prep_kernel, dim3(BATCH_N / 4), dim3(256), 0, stream, ids, mem, emb, x);
    hipLaunchKernelGGL(gemm_kernel, dim3(NWG), dim3(512), 0, stream,
                       x, wt, bq, bs, bk, out);
}